// Round 1
// baseline (1162.906 us; speedup 1.0000x reference)
//
#include <hip/hip_runtime.h>

constexpr int kS = 1024;

// ---------------------------------------------------------------------------
// Generic fp32 GEMM:  C[m][n] = sum_k A[m][k] * B[n][k]  (+ bias[n])
// tiles 128x128, K-step 32, 256 threads, 8x8 per thread.
// batch offsets: offA = (z/16)*sAo + (z%16)*sAi (same for B), offC = z*sC
// ---------------------------------------------------------------------------
__global__ __launch_bounds__(256) void gemm_nt(
    const float* __restrict__ A, const float* __restrict__ Bm,
    const float* __restrict__ bias, float* __restrict__ C,
    int K, int lda, int ldb, int ldc,
    long sAo, long sAi, long sBo, long sBi, long sC)
{
    __shared__ float As[32][132];
    __shared__ float Bs[32][132];
    const int t = threadIdx.x;
    const int z = blockIdx.z;
    const long offA = (long)(z >> 4) * sAo + (long)(z & 15) * sAi;
    const long offB = (long)(z >> 4) * sBo + (long)(z & 15) * sBi;
    const long offC = (long)z * sC;
    const int m0 = blockIdx.y * 128;
    const int n0 = blockIdx.x * 128;
    const int sr = t >> 3;          // 0..31
    const int sc = (t & 7) << 2;    // 0..28
    const int tx = t & 15, ty = t >> 4;

    float acc[8][8];
#pragma unroll
    for (int i = 0; i < 8; ++i)
#pragma unroll
        for (int j = 0; j < 8; ++j) acc[i][j] = 0.f;

    for (int k0 = 0; k0 < K; k0 += 32) {
#pragma unroll
        for (int r = 0; r < 4; ++r) {
            const int m = sr + 32 * r;
            const float4 av = *(const float4*)&A[offA + (long)(m0 + m) * lda + k0 + sc];
            As[sc + 0][m] = av.x; As[sc + 1][m] = av.y;
            As[sc + 2][m] = av.z; As[sc + 3][m] = av.w;
            const float4 bv = *(const float4*)&Bm[offB + (long)(n0 + m) * ldb + k0 + sc];
            Bs[sc + 0][m] = bv.x; Bs[sc + 1][m] = bv.y;
            Bs[sc + 2][m] = bv.z; Bs[sc + 3][m] = bv.w;
        }
        __syncthreads();
#pragma unroll 4
        for (int kk = 0; kk < 32; ++kk) {
            float a8[8], b8[8];
            *(float4*)&a8[0] = *(const float4*)&As[kk][ty * 8];
            *(float4*)&a8[4] = *(const float4*)&As[kk][ty * 8 + 4];
            *(float4*)&b8[0] = *(const float4*)&Bs[kk][tx * 8];
            *(float4*)&b8[4] = *(const float4*)&Bs[kk][tx * 8 + 4];
#pragma unroll
            for (int i = 0; i < 8; ++i)
#pragma unroll
                for (int j = 0; j < 8; ++j)
                    acc[i][j] = fmaf(a8[i], b8[j], acc[i][j]);
        }
        __syncthreads();
    }

    float bv[8];
#pragma unroll
    for (int j = 0; j < 8; ++j) bv[j] = bias ? bias[n0 + tx * 8 + j] : 0.f;
#pragma unroll
    for (int i = 0; i < 8; ++i) {
        float o[8];
#pragma unroll
        for (int j = 0; j < 8; ++j) o[j] = acc[i][j] + bv[j];
        float* cp = &C[offC + (long)(m0 + ty * 8 + i) * ldc + n0 + tx * 8];
        *(float4*)&cp[0] = *(const float4*)&o[0];
        *(float4*)&cp[4] = *(const float4*)&o[4];
    }
}

// ---------------------------------------------------------------------------
// qrel2[b,s,m,j] = sum_n tw[n][m] * ( sum_d q[b,s,n,d] * W_rel[j][d] )
// one block per (b,s)
// ---------------------------------------------------------------------------
__global__ __launch_bounds__(256) void qrel2_kernel(
    const float* __restrict__ qproj, const float* __restrict__ W_rel,
    const float* __restrict__ tw, float* __restrict__ qrel2)
{
    __shared__ float qrow[1024];     // [n][d]
    __shared__ float wrT[64 * 66];   // [d][j], padded stride 66
    __shared__ float twl[256];
    __shared__ float qr[16 * 65];    // [n][j]
    const int t = threadIdx.x;
    const long bs = blockIdx.x;
    const float* qp = qproj + bs * 1024;
    for (int i = t; i < 1024; i += 256) qrow[i] = qp[i];
    for (int i = t; i < 65 * 64; i += 256) {
        const int j = i >> 6, d = i & 63;
        wrT[d * 66 + j] = W_rel[i];
    }
    twl[t] = tw[t];
    __syncthreads();
    for (int p = t; p < 16 * 65; p += 256) {
        const int n = p / 65, j = p % 65;
        float s = 0.f;
#pragma unroll 8
        for (int d = 0; d < 64; ++d) s = fmaf(qrow[n * 64 + d], wrT[d * 66 + j], s);
        qr[n * 65 + j] = s;
    }
    __syncthreads();
    for (int p = t; p < 16 * 65; p += 256) {
        const int m = p / 65, j = p % 65;
        float s = 0.f;
#pragma unroll
        for (int n = 0; n < 16; ++n) s = fmaf(twl[n * 16 + m], qr[n * 65 + j], s);
        qrel2[bs * (16 * 65) + p] = s;
    }
}

// ---------------------------------------------------------------------------
// mix: in-place pre -> scores ([B][H][S][S]) + per-(row, k-chunk) softmax
// partials. grid (kc=4, q=1024, b=2), 256 threads = 256 consecutive k.
// ---------------------------------------------------------------------------
__global__ __launch_bounds__(256) void mix_kernel(
    float* __restrict__ scores, const float* __restrict__ qrel2,
    const float* __restrict__ tw, const unsigned char* __restrict__ mask,
    const int* __restrict__ qpos, const int* __restrict__ kpos,
    float* __restrict__ statp)
{
    __shared__ float qr2[16 * 65];
    __shared__ float twl[256];
    __shared__ float cm[16];
    __shared__ float redm[4][16];
    __shared__ float reds[4][16];
    __shared__ float gmax[16];
    const int t = threadIdx.x;
    const int kc = blockIdx.x;
    const int q = blockIdx.y;
    const int b = blockIdx.z;
    const int k = kc * 256 + t;

    const float* q2p = qrel2 + (long)(b * kS + q) * (16 * 65);
    for (int i = t; i < 16 * 65; i += 256) qr2[i] = q2p[i];
    twl[t] = tw[t];
    __syncthreads();
    if (t < 16) {  // cm[m] = sum_n slopes[n]*tw[n][m], slopes[n] = start^(n+1)
        float s = 0.f, cur = 0.7071067811865476f;
        for (int n = 0; n < 16; ++n) { s = fmaf(cur, twl[n * 16 + t], s); cur *= 0.7071067811865476f; }
        cm[t] = s;
    }
    __syncthreads();

    const int rel = qpos[b * kS + q] - kpos[b * kS + k];
    const int idxc = (rel < -32 ? -32 : (rel > 32 ? 32 : rel)) + 32;
    const float ab = fabsf((float)rel);
    const bool msk = mask[((long)b * kS + q) * kS + k] != 0;

    float pre[16];
#pragma unroll
    for (int n = 0; n < 16; ++n)
        pre[n] = scores[((long)(b * 16 + n) * kS + q) * kS + k];
    float sm[16];
#pragma unroll
    for (int m = 0; m < 16; ++m) sm[m] = 0.f;
#pragma unroll
    for (int n = 0; n < 16; ++n) {
        const float p = pre[n];
#pragma unroll
        for (int m = 0; m < 16; ++m) sm[m] = fmaf(p, twl[n * 16 + m], sm[m]);
    }
#pragma unroll
    for (int m = 0; m < 16; ++m) {
        float v = (sm[m] + qr2[m * 65 + idxc] + ab * cm[m]) * 0.125f;
        v = msk ? -10000.f : v;
        sm[m] = v;
        scores[((long)(b * 16 + m) * kS + q) * kS + k] = v;
    }

    // partial softmax stats over this block's 256 k
    const int lane = t & 63, wv = t >> 6;
    float mx[16];
#pragma unroll
    for (int m = 0; m < 16; ++m) mx[m] = sm[m];
#pragma unroll
    for (int m = 0; m < 16; ++m)
        for (int d = 1; d < 64; d <<= 1)
            mx[m] = fmaxf(mx[m], __shfl_xor(mx[m], d, 64));
    if (lane == 0)
        for (int m = 0; m < 16; ++m) redm[wv][m] = mx[m];
    __syncthreads();
    if (t < 16) {
        float v = redm[0][t];
        for (int w = 1; w < 4; ++w) v = fmaxf(v, redm[w][t]);
        gmax[t] = v;
    }
    __syncthreads();
    float sx[16];
#pragma unroll
    for (int m = 0; m < 16; ++m) sx[m] = expf(sm[m] - gmax[m]);
#pragma unroll
    for (int m = 0; m < 16; ++m)
        for (int d = 1; d < 64; d <<= 1)
            sx[m] += __shfl_xor(sx[m], d, 64);
    if (lane == 0)
        for (int m = 0; m < 16; ++m) reds[wv][m] = sx[m];
    __syncthreads();
    if (t < 16) {
        const float l = reds[0][t] + reds[1][t] + reds[2][t] + reds[3][t];
        float2* sp = (float2*)statp;
        sp[((long)(b * 16 + t) * kS + q) * 4 + kc] = make_float2(gmax[t], l);
    }
}

// ---------------------------------------------------------------------------
// combine 4 partials -> (M, 1/l) per (b,h,q) row
// ---------------------------------------------------------------------------
__global__ __launch_bounds__(256) void stats_final(
    const float* __restrict__ statp, float* __restrict__ stats)
{
    const int r = blockIdx.x * 256 + threadIdx.x;  // 0..32767
    const float* p = statp + (long)r * 8;
    float M = -1e30f;
#pragma unroll
    for (int i = 0; i < 4; ++i) M = fmaxf(M, p[i * 2]);
    float l = 0.f;
#pragma unroll
    for (int i = 0; i < 4; ++i) l += p[i * 2 + 1] * expf(p[i * 2] - M);
    l = fmaxf(l, 1e-30f);
    stats[r * 2] = M;
    stats[r * 2 + 1] = 1.f / l;
}

// ---------------------------------------------------------------------------
// attn + PV + rel-pos value term.  grid (qt=16, h=16, b=2), 256 threads.
// 64 q-rows x full k per block; k-tiles of 64.
// out2 uses arange-position bucket structure (middle buckets are singletons).
// ---------------------------------------------------------------------------
__global__ __launch_bounds__(256) void attn_pv(
    const float* __restrict__ scores, float* __restrict__ attn,
    const float* __restrict__ vproj, const float* __restrict__ wrel_g,
    const float* __restrict__ stats, float* __restrict__ head_out)
{
    __shared__ float atT[64][68];     // transposed attn tile [k][q]
    __shared__ float vs[64][64];      // v tile [k][d]  (aliased as pv partial later)
    __shared__ float amid[64][64];    // middle-bucket gather [q][j]
    __shared__ float red_lo[64][16];
    __shared__ float red_hi[64][16];
    __shared__ float MR[64][2];
    __shared__ float wrl[65 * 64];

    const int t = threadIdx.x;
    const int q0 = blockIdx.x * 64;
    const int h = blockIdx.y;
    const int b = blockIdx.z;

    if (t < 64) {
        const float2 s2 = ((const float2*)stats)[(long)(b * 16 + h) * kS + q0 + t];
        MR[t][0] = s2.x; MR[t][1] = s2.y;
    }
    for (int i = t; i < 65 * 64; i += 256) wrl[i] = wrel_g[i];
    {
        float* amf = &amid[0][0];
        for (int i = t; i < 64 * 64; i += 256) amf[i] = 0.f;
    }

    const int g = t >> 7;            // k-half group for PV
    const int u = t & 127;
    const int txd = u & 15, tyq = u >> 4;
    const int qs = tyq * 8, ds = txd * 4;
    const int korg = g * 32;
    const int arow = t >> 4;         // 0..15
    const int akq = (t & 15) * 4;    // 0..60

    float acc[8][4];
#pragma unroll
    for (int i = 0; i < 8; ++i)
#pragma unroll
        for (int j = 0; j < 4; ++j) acc[i][j] = 0.f;
    float slo[4] = {0.f, 0.f, 0.f, 0.f};
    float shi[4] = {0.f, 0.f, 0.f, 0.f};

    const long scb = (long)(b * 16 + h) * kS;
    for (int kt = 0; kt < 16; ++kt) {
        const int k0 = kt * 64;
        __syncthreads();
        // stage v tile
#pragma unroll
        for (int r = 0; r < 4; ++r) {
            const int krow = arow + 16 * r;
            const float4 vv = *(const float4*)&vproj[(((long)(b * kS + k0 + krow)) * 16 + h) * 64 + akq];
            *(float4*)&vs[krow][akq] = vv;
        }
        // attn phase
#pragma unroll
        for (int r = 0; r < 4; ++r) {
            const int qrow = arow + 16 * r;
            const int qg = q0 + qrow;
            const long off = (scb + qg) * kS + k0 + akq;
            const float4 s4 = *(const float4*)&scores[off];
            const float M = MR[qrow][0], R = MR[qrow][1];
            const float a0 = expf(s4.x - M) * R;
            const float a1 = expf(s4.y - M) * R;
            const float a2 = expf(s4.z - M) * R;
            const float a3 = expf(s4.w - M) * R;
            const float4 a4o = make_float4(a0, a1, a2, a3);
            *(float4*)&attn[off] = a4o;
            atT[akq + 0][qrow] = a0;
            atT[akq + 1][qrow] = a1;
            atT[akq + 2][qrow] = a2;
            atT[akq + 3][qrow] = a3;
            const float av[4] = {a0, a1, a2, a3};
#pragma unroll
            for (int j = 0; j < 4; ++j) {
                const int kg = k0 + akq + j;
                const int jj = qg - kg + 32;
                if (jj >= 1 && jj <= 63) amid[qrow][jj] = av[j];
                else if (jj >= 64) slo[r] += av[j];
                else shi[r] += av[j];
            }
        }
        __syncthreads();
        // PV accumulate (each group half the k-tile)
#pragma unroll 4
        for (int kk = 0; kk < 32; ++kk) {
            const int k = korg + kk;
            float a8[8], v4[4];
            *(float4*)&a8[0] = *(const float4*)&atT[k][qs];
            *(float4*)&a8[4] = *(const float4*)&atT[k][qs + 4];
            *(float4*)&v4[0] = *(const float4*)&vs[k][ds];
#pragma unroll
            for (int i = 0; i < 8; ++i)
#pragma unroll
                for (int j = 0; j < 4; ++j)
                    acc[i][j] = fmaf(a8[i], v4[j], acc[i][j]);
        }
    }
    __syncthreads();
    float* pvp = &vs[0][0];
    if (g == 1) {
#pragma unroll
        for (int i = 0; i < 8; ++i)
#pragma unroll
            for (int j = 0; j < 4; ++j) pvp[u * 32 + i * 4 + j] = acc[i][j];
    }
#pragma unroll
    for (int r = 0; r < 4; ++r) {
        const int qrow = arow + 16 * r;
        red_lo[qrow][t & 15] = slo[r];
        red_hi[qrow][t & 15] = shi[r];
    }
    __syncthreads();
    if (g == 0) {
#pragma unroll
        for (int i = 0; i < 8; ++i)
#pragma unroll
            for (int j = 0; j < 4; ++j) acc[i][j] += pvp[u * 32 + i * 4 + j];
#pragma unroll
        for (int i = 0; i < 8; ++i) {
            const int qrow = qs + i;
            float Sl = 0.f, Sh = 0.f;
#pragma unroll
            for (int l = 0; l < 16; ++l) { Sl += red_lo[qrow][l]; Sh += red_hi[qrow][l]; }
#pragma unroll
            for (int j = 0; j < 4; ++j)
                acc[i][j] += Sh * wrl[ds + j] + Sl * wrl[64 * 64 + ds + j];
        }
        for (int jj = 1; jj < 64; ++jj) {
            float wv[4];
            *(float4*)&wv[0] = *(const float4*)&wrl[jj * 64 + ds];
#pragma unroll
            for (int i = 0; i < 8; ++i) {
                const float am = amid[qs + i][jj];
#pragma unroll
                for (int j = 0; j < 4; ++j) acc[i][j] = fmaf(am, wv[j], acc[i][j]);
            }
        }
#pragma unroll
        for (int i = 0; i < 8; ++i) {
            float* op = &head_out[(((long)(b * kS + q0 + qs + i)) * 16 + h) * 64 + ds];
            *(float4*)&op[0] = *(const float4*)&acc[i][0];
        }
    }
}

// ---------------------------------------------------------------------------
extern "C" void kernel_launch(void* const* d_in, const int* in_sizes, int n_in,
                              void* d_out, int out_size, void* d_ws, size_t ws_size,
                              hipStream_t stream)
{
    const float* q_in = (const float*)d_in[0];
    const float* k_in = (const float*)d_in[1];
    const float* v_in = (const float*)d_in[2];
    const unsigned char* mask = (const unsigned char*)d_in[3];
    const int* qpos = (const int*)d_in[4];
    const int* kpos = (const int*)d_in[5];
    const float* W_q = (const float*)d_in[6];
    const float* b_q = (const float*)d_in[7];
    const float* W_k = (const float*)d_in[8];
    const float* b_k = (const float*)d_in[9];
    const float* W_v = (const float*)d_in[10];
    const float* b_v = (const float*)d_in[11];
    const float* W_o = (const float*)d_in[12];
    const float* b_o = (const float*)d_in[13];
    const float* W_rel = (const float*)d_in[14];
    const float* tw = (const float*)d_in[15];

    float* ws = (float*)d_ws;
    float* qb = ws;                    // 2,097,152
    float* kb = qb + 2097152;
    float* vb = kb + 2097152;
    float* q2 = vb + 2097152;          // 2,129,920
    float* statp = q2 + 2129920;       // 262,144
    float* stats = statp + 262144;     // 65,536
    float* hout = stats + 65536;       // 2,097,152

    float* out = (float*)d_out;
    float* attn = out + 2097152;
    float* scores = attn + 33554432;

    const dim3 blk(256, 1, 1);
    const dim3 gp(8, 16, 1);
    // projections
    gemm_nt<<<gp, blk, 0, stream>>>(q_in, W_q, b_q, qb, 1024, 1024, 1024, 1024, 0L, 0L, 0L, 0L, 0L);
    gemm_nt<<<gp, blk, 0, stream>>>(k_in, W_k, b_k, kb, 1024, 1024, 1024, 1024, 0L, 0L, 0L, 0L, 0L);
    gemm_nt<<<gp, blk, 0, stream>>>(v_in, W_v, b_v, vb, 1024, 1024, 1024, 1024, 0L, 0L, 0L, 0L, 0L);
    // relative-pos projection (talking-heads pre-mixed)
    qrel2_kernel<<<dim3(2048, 1, 1), blk, 0, stream>>>(qb, W_rel, tw, q2);
    // pre-scores = q_n k_n^T, written into scores region of d_out (in-place later)
    const dim3 gpre(8, 8, 32);
    gemm_nt<<<gpre, blk, 0, stream>>>(qb, kb, (const float*)nullptr, scores,
                                      64, 1024, 1024, 1024,
                                      1048576L, 64L, 1048576L, 64L, 1048576L);
    // talking-heads mix + rel-pos + alibi + scale + mask (+ softmax partials)
    const dim3 gmix(4, 1024, 2);
    mix_kernel<<<gmix, blk, 0, stream>>>(scores, q2, tw, mask, qpos, kpos, statp);
    stats_final<<<dim3(128, 1, 1), blk, 0, stream>>>(statp, stats);
    // attn + PV + positional value term
    const dim3 gk4(16, 16, 2);
    attn_pv<<<gk4, blk, 0, stream>>>(scores, attn, vb, W_rel, stats, hout);
    // output projection
    gemm_nt<<<gp, blk, 0, stream>>>(hout, W_o, b_o, out, 1024, 1024, 1024, 1024, 0L, 0L, 0L, 0L, 0L);
}